// Round 1
// baseline (412.584 us; speedup 1.0000x reference)
//
#include <hip/hip_runtime.h>
#include <math.h>

#define BB 4
#define NSZ 2048
#define FDIM 128
#define ODIM 32
#define HH 8
#define NEG 0.2f
#define MSHIFT 16.0f

// workspace layout (float units)
#define WS_WH    0                       // [B][H][N][O]   = 2097152 floats
#define WS_ASRC  2097152                 // [B][H][N]      = 65536
#define WS_ADST  2162688                 // [B][H][N]      = 65536
#define WS_ADJB  2228224                 // [B][N][64] u32 = 524288 words

// ---------------------------------------------------------------------------
// Kernel A: pack (adj + I > 0) into bitmask words. 8 lanes cooperate per word.
// ---------------------------------------------------------------------------
__global__ __launch_bounds__(256) void k_adjbits(const float* __restrict__ adj,
                                                 unsigned* __restrict__ adjb) {
    int g = blockIdx.x * 256 + threadIdx.x;     // [0, B*N*64*8)
    int l = g & 7;                              // lane within 8-group
    int word = g >> 3;                          // [0, B*N*64)
    int wk = word & 63;
    int row = word >> 6;                        // b*N + i
    int i = row & (NSZ - 1);
    const float4 v = *(const float4*)&adj[(size_t)row * NSZ + wk * 32 + l * 4];
    unsigned m = 0;
    if (v.x > 0.f) m |= 1u << (l * 4 + 0);
    if (v.y > 0.f) m |= 1u << (l * 4 + 1);
    if (v.z > 0.f) m |= 1u << (l * 4 + 2);
    if (v.w > 0.f) m |= 1u << (l * 4 + 3);
    m |= (unsigned)__shfl_xor((int)m, 1);
    m |= (unsigned)__shfl_xor((int)m, 2);
    m |= (unsigned)__shfl_xor((int)m, 4);
    if (l == 0) {
        int jb = i - wk * 32;
        if (jb >= 0 && jb < 32) m |= 1u << jb;  // self-loop
        adjb[word] = m;
    }
}

// ---------------------------------------------------------------------------
// Kernel 1: Wh = x @ W per head, plus alpha_src/alpha_dst dot products.
// Block = (b, 8-row n-tile); thread = (h, o).
// ---------------------------------------------------------------------------
__global__ __launch_bounds__(256) void k_wh(const float* __restrict__ x,
                                            const float* __restrict__ W,
                                            const float* __restrict__ a_src,
                                            const float* __restrict__ a_dst,
                                            float* __restrict__ Wh,
                                            float* __restrict__ asrc,
                                            float* __restrict__ adst) {
    __shared__ float xl[8 * FDIM];
    int t = threadIdx.x;
    int b = blockIdx.y;
    int n0 = blockIdx.x * 8;
    // stage 8 x-rows (1024 floats) coalesced
    ((float4*)xl)[t] = ((const float4*)(x + (size_t)(b * NSZ + n0) * FDIM))[t];
    __syncthreads();

    int h = t >> 5, o = t & 31;
    float acc[8];
#pragma unroll
    for (int nn = 0; nn < 8; nn++) acc[nn] = 0.f;

    const float* wp = W + (size_t)h * FDIM * ODIM + o;
#pragma unroll 4
    for (int f = 0; f < FDIM; f += 4) {
        float w0 = wp[(f + 0) * ODIM];
        float w1 = wp[(f + 1) * ODIM];
        float w2 = wp[(f + 2) * ODIM];
        float w3 = wp[(f + 3) * ODIM];
#pragma unroll
        for (int nn = 0; nn < 8; nn++) {
            float4 xv = *(const float4*)&xl[nn * FDIM + f];
            acc[nn] += xv.x * w0 + xv.y * w1 + xv.z * w2 + xv.w * w3;
        }
    }

    float as = a_src[h * ODIM + o];
    float ad = a_dst[h * ODIM + o];
#pragma unroll
    for (int nn = 0; nn < 8; nn++) {
        float wv = acc[nn];
        Wh[((size_t)(b * HH + h) * NSZ + n0 + nn) * ODIM + o] = wv;
        float vs = wv * as;
        float vd = wv * ad;
#pragma unroll
        for (int mk = 16; mk; mk >>= 1) {
            vs += __shfl_xor(vs, mk);
            vd += __shfl_xor(vd, mk);
        }
        if (o == 0) {
            asrc[(size_t)(b * HH + h) * NSZ + n0 + nn] = vs;
            adst[(size_t)(b * HH + h) * NSZ + n0 + nn] = vd;
        }
    }
}

// ---------------------------------------------------------------------------
// Kernel 2: fused masked-softmax aggregation (flash-style, no score matrix).
// Block = (b, 32-row i-tile), all 8 heads. 256 threads.
// Phase 1 (thread = (h, j)): p[h][j][i] = mask ? exp(lrelu(asrc_i+adst_j)-16) : 0
//   written to LDS as swizzled float4 chunks (chunk c -> c ^ (j&7)).
// Phase 2 (thread = (h, ig, og)): 4i x 8o register tile, 32 FMA per
//   ds_read_b128 of p + broadcast float4 Wh loads.
// ---------------------------------------------------------------------------
__global__ __launch_bounds__(256) void k_gat(const float* __restrict__ Wh,
                                             const float* __restrict__ asrc,
                                             const float* __restrict__ adst,
                                             const unsigned* __restrict__ adjb,
                                             float* __restrict__ out) {
    __shared__ float plds[8 * 32 * 32];   // [h][j][i] (i in swizzled float4 chunks)
    __shared__ float asl[8 * 32];

    int t = threadIdx.x;
    int b = blockIdx.y;
    int i0 = blockIdx.x * 32;

    {   // stage asrc for this tile: [h][i]
        int hh = t >> 5, ii = t & 31;
        asl[t] = asrc[(size_t)(b * HH + hh) * NSZ + i0 + ii];
    }

    int h = t >> 5;
    int jj = t & 31;                 // phase-1 role: j lane
    int sub = t & 31;
    int ig = sub >> 2, og = sub & 3; // phase-2 role: 4-i group, 8-o group

    float acc[4][8];
    float den[4];
#pragma unroll
    for (int r = 0; r < 4; r++) {
        den[r] = 0.f;
#pragma unroll
        for (int k = 0; k < 8; k++) acc[r][k] = 0.f;
    }

    const float* adp = adst + (size_t)(b * HH + h) * NSZ;
    const float* whp = Wh + (size_t)(b * HH + h) * NSZ * ODIM + og * 8;
    const unsigned* abp = adjb + (size_t)(b * NSZ + i0) * 64;

    __syncthreads();

    for (int wk = 0; wk < 64; wk++) {
        int j0 = wk * 32;
        // ---- phase 1: compute p tile ----
        float adv = adp[j0 + jj];
#pragma unroll
        for (int c = 0; c < 8; c++) {
            float4 pv;
            float pr[4];
#pragma unroll
            for (int r = 0; r < 4; r++) {
                int i = c * 4 + r;
                unsigned w = abp[i * 64 + wk];          // uniform -> s_load
                float s = asl[h * 32 + i] + adv;
                float e = s >= 0.f ? s : NEG * s;
                float p = __expf(e - MSHIFT);
                pr[r] = ((w >> jj) & 1u) ? p : 0.f;
            }
            pv.x = pr[0]; pv.y = pr[1]; pv.z = pr[2]; pv.w = pr[3];
            ((float4*)plds)[h * 256 + jj * 8 + (c ^ (jj & 7))] = pv;
        }
        __syncthreads();
        // ---- phase 2: accumulate ----
#pragma unroll 4
        for (int j = 0; j < 32; j++) {
            float4 p4 = ((const float4*)plds)[h * 256 + j * 8 + (ig ^ (j & 7))];
            const float* wj = whp + (size_t)(j0 + j) * ODIM;
            float4 wa = *(const float4*)wj;
            float4 wb = *(const float4*)(wj + 4);
            float pr[4] = {p4.x, p4.y, p4.z, p4.w};
            float wv[8] = {wa.x, wa.y, wa.z, wa.w, wb.x, wb.y, wb.z, wb.w};
#pragma unroll
            for (int r = 0; r < 4; r++) {
                den[r] += pr[r];
#pragma unroll
                for (int k = 0; k < 8; k++) acc[r][k] += pr[r] * wv[k];
            }
        }
        __syncthreads();
    }

    // ---- epilogue: out[b][i][h*32 + o] = relu(acc/den) ----
#pragma unroll
    for (int r = 0; r < 4; r++) {
        int i = i0 + ig * 4 + r;
        float inv = 1.0f / den[r];
        float4 o1, o2;
        o1.x = fmaxf(acc[r][0] * inv, 0.f);
        o1.y = fmaxf(acc[r][1] * inv, 0.f);
        o1.z = fmaxf(acc[r][2] * inv, 0.f);
        o1.w = fmaxf(acc[r][3] * inv, 0.f);
        o2.x = fmaxf(acc[r][4] * inv, 0.f);
        o2.y = fmaxf(acc[r][5] * inv, 0.f);
        o2.z = fmaxf(acc[r][6] * inv, 0.f);
        o2.w = fmaxf(acc[r][7] * inv, 0.f);
        float* op = out + (size_t)(b * NSZ + i) * (HH * ODIM) + h * ODIM + og * 8;
        *(float4*)op = o1;
        *(float4*)(op + 4) = o2;
    }
}

extern "C" void kernel_launch(void* const* d_in, const int* in_sizes, int n_in,
                              void* d_out, int out_size, void* d_ws, size_t ws_size,
                              hipStream_t stream) {
    const float* x     = (const float*)d_in[0];
    const float* adj   = (const float*)d_in[1];
    const float* W     = (const float*)d_in[2];
    const float* a_src = (const float*)d_in[3];
    const float* a_dst = (const float*)d_in[4];
    float* out = (float*)d_out;

    float* ws = (float*)d_ws;
    float* Wh    = ws + WS_WH;
    float* asrc  = ws + WS_ASRC;
    float* adst  = ws + WS_ADST;
    unsigned* adjb = (unsigned*)(ws + WS_ADJB);

    // adj bitmask: B*N*64 words, 8 lanes/word
    k_adjbits<<<dim3((BB * NSZ * 64 * 8) / 256), dim3(256), 0, stream>>>(adj, adjb);
    // projection + alphas
    k_wh<<<dim3(NSZ / 8, BB), dim3(256), 0, stream>>>(x, W, a_src, a_dst, Wh, asrc, adst);
    // fused masked softmax + aggregation
    k_gat<<<dim3(NSZ / 32, BB), dim3(256), 0, stream>>>(Wh, asrc, adst, adjb, out);
}

// Round 2
// 182.556 us; speedup vs baseline: 2.2600x; 2.2600x over previous
//
#include <hip/hip_runtime.h>
#include <math.h>

#define BB 4
#define NSZ 2048
#define FDIM 128
#define ODIM 32
#define HH 8
#define NEG 0.2f
#define MSHIFT 16.0f

typedef short short8 __attribute__((ext_vector_type(8)));
typedef float f32x4 __attribute__((ext_vector_type(4)));

// workspace layout (float units)
#define WS_ASRC 0                 // [B][H][N]        = 65536 floats
#define WS_ADST 65536             // [B][H][N]        = 65536 floats
#define WS_ADJB 131072            // [B][N][64] u32   = 524288 words
#define WS_WHF  655360            // bf16 B-fragments = 1048576 floats (4 MB)
// whf layout: int4[ ((b*H+h)*64 + jt)*2 + ot ][ 64 lanes ]  (16 B per lane-frag)

// round-to-nearest-even float -> bf16, result in TOP 16 bits
__device__ __forceinline__ unsigned bfbits(float f) {
    unsigned u = __builtin_bit_cast(unsigned, f);
    return u + 0x7fffu + ((u >> 16) & 1u);
}

// ---------------------------------------------------------------------------
// Kernel A: pack (adj + I > 0) into bitmask words. 8 lanes cooperate per word.
// ---------------------------------------------------------------------------
__global__ __launch_bounds__(256) void k_adjbits(const float* __restrict__ adj,
                                                 unsigned* __restrict__ adjb) {
    int g = blockIdx.x * 256 + threadIdx.x;     // [0, B*N*64*8)
    int l = g & 7;                              // lane within 8-group
    int word = g >> 3;                          // [0, B*N*64)
    int wk = word & 63;
    int row = word >> 6;                        // b*N + i
    int i = row & (NSZ - 1);
    const float4 v = *(const float4*)&adj[(size_t)row * NSZ + wk * 32 + l * 4];
    unsigned m = 0;
    if (v.x > 0.f) m |= 1u << (l * 4 + 0);
    if (v.y > 0.f) m |= 1u << (l * 4 + 1);
    if (v.z > 0.f) m |= 1u << (l * 4 + 2);
    if (v.w > 0.f) m |= 1u << (l * 4 + 3);
    m |= (unsigned)__shfl_xor((int)m, 1);
    m |= (unsigned)__shfl_xor((int)m, 2);
    m |= (unsigned)__shfl_xor((int)m, 4);
    if (l == 0) {
        int jb = i - wk * 32;
        if (jb >= 0 && jb < 32) m |= 1u << jb;  // self-loop
        adjb[word] = m;
    }
}

// ---------------------------------------------------------------------------
// Kernel 1: Wh = x @ W per head + alpha dot products. Emits Wh pre-packed in
// bf16 MFMA B-fragment order: element j of lane (quad*16+col) = wh[n0+j][o],
// i.e. B[k = quad*8+j][n = o&15] for j-tile jt = n0/32, otile = o/16.
// Block = (b, 8-row n-tile); thread = (h, o).
// ---------------------------------------------------------------------------
__global__ __launch_bounds__(256) void k_wh(const float* __restrict__ x,
                                            const float* __restrict__ W,
                                            const float* __restrict__ a_src,
                                            const float* __restrict__ a_dst,
                                            int4* __restrict__ whf,
                                            float* __restrict__ asrc,
                                            float* __restrict__ adst) {
    __shared__ float xl[8 * FDIM];
    int t = threadIdx.x;
    int b = blockIdx.y;
    int n0 = blockIdx.x * 8;
    // stage 8 x-rows (1024 floats) coalesced
    ((float4*)xl)[t] = ((const float4*)(x + (size_t)(b * NSZ + n0) * FDIM))[t];
    __syncthreads();

    int h = t >> 5, o = t & 31;
    float acc[8];
#pragma unroll
    for (int nn = 0; nn < 8; nn++) acc[nn] = 0.f;

    const float* wp = W + (size_t)h * FDIM * ODIM + o;
#pragma unroll 4
    for (int f = 0; f < FDIM; f += 4) {
        float w0 = wp[(f + 0) * ODIM];
        float w1 = wp[(f + 1) * ODIM];
        float w2 = wp[(f + 2) * ODIM];
        float w3 = wp[(f + 3) * ODIM];
#pragma unroll
        for (int nn = 0; nn < 8; nn++) {
            float4 xv = *(const float4*)&xl[nn * FDIM + f];
            acc[nn] += xv.x * w0 + xv.y * w1 + xv.z * w2 + xv.w * w3;
        }
    }

    float as = a_src[h * ODIM + o];
    float ad = a_dst[h * ODIM + o];
#pragma unroll
    for (int nn = 0; nn < 8; nn++) {
        float vs = acc[nn] * as;
        float vd = acc[nn] * ad;
#pragma unroll
        for (int mk = 16; mk; mk >>= 1) {
            vs += __shfl_xor(vs, mk);
            vd += __shfl_xor(vd, mk);
        }
        if (o == 0) {
            asrc[(size_t)(b * HH + h) * NSZ + n0 + nn] = vs;
            adst[(size_t)(b * HH + h) * NSZ + n0 + nn] = vd;
        }
    }

    // pack 8 bf16 (element j = acc[j]) and store one 16B fragment chunk
    int jt = n0 >> 5;
    int quad = (n0 >> 3) & 3;
    int ot = o >> 4;
    int lane = quad * 16 + (o & 15);
    unsigned d0 = (bfbits(acc[0]) >> 16) | (bfbits(acc[1]) & 0xffff0000u);
    unsigned d1 = (bfbits(acc[2]) >> 16) | (bfbits(acc[3]) & 0xffff0000u);
    unsigned d2 = (bfbits(acc[4]) >> 16) | (bfbits(acc[5]) & 0xffff0000u);
    unsigned d3 = (bfbits(acc[6]) >> 16) | (bfbits(acc[7]) & 0xffff0000u);
    whf[(((size_t)(b * HH + h) * 64 + jt) * 2 + ot) * 64 + lane] =
        make_int4((int)d0, (int)d1, (int)d2, (int)d3);
}

// ---------------------------------------------------------------------------
// Kernel 2: fused masked-softmax aggregation via MFMA. No LDS, no barriers.
// One wave = (b, h, 16-row i-tile). Per 32-j tile: compute p in A-fragment
// layout (A[m=lane&15][k=(lane>>4)*8+j], verified m89/m91), load pre-packed
// bf16 B-fragments of Wh (coalesced dwordx4), 2x mfma_16x16x32_bf16.
// den accumulated from the same bf16-rounded p (softmax stays convex).
// ---------------------------------------------------------------------------
__global__ __launch_bounds__(256) void k_gat(const int4* __restrict__ whf,
                                             const float* __restrict__ asrc,
                                             const float* __restrict__ adst,
                                             const unsigned* __restrict__ adjb,
                                             float* __restrict__ out) {
    int lane = threadIdx.x & 63;
    int wid = blockIdx.x * 4 + (threadIdx.x >> 6);   // [0, 4096)
    int i0 = (wid & 127) << 4;
    int h = (wid >> 7) & 7;
    int b = wid >> 10;
    int col = lane & 15;
    int quad = lane >> 4;

    float as_i = asrc[(size_t)(b * HH + h) * NSZ + i0 + col];
    const float* adp = adst + (size_t)(b * HH + h) * NSZ + quad * 8;
    const unsigned* abp = adjb + ((size_t)(b * NSZ) + i0 + col) * 64;
    const int4* bfp = whf + (size_t)(b * HH + h) * 8192 + lane;

    f32x4 acc0 = {0.f, 0.f, 0.f, 0.f};
    f32x4 acc1 = {0.f, 0.f, 0.f, 0.f};
    float den = 0.f;
    int qsh = quad * 8;

    for (int jt = 0; jt < 64; jt++) {
        unsigned w = abp[jt] >> qsh;                 // mask bits for this lane's 8 j's
        float4 a0 = *(const float4*)&adp[jt * 32];
        float4 a1 = *(const float4*)&adp[jt * 32 + 4];
        int4 blo = bfp[jt * 128];                    // B-frag, o 0..15
        int4 bhi = bfp[jt * 128 + 64];               // B-frag, o 16..31
        float av[8] = {a0.x, a0.y, a0.z, a0.w, a1.x, a1.y, a1.z, a1.w};
        unsigned dw[4];
#pragma unroll
        for (int pp = 0; pp < 4; pp++) {
            float s0 = as_i + av[2 * pp];
            float s1 = as_i + av[2 * pp + 1];
            float e0 = fmaxf(s0, NEG * s0);          // leaky_relu
            float e1 = fmaxf(s1, NEG * s1);
            float p0 = __expf(e0 - MSHIFT);
            float p1 = __expf(e1 - MSHIFT);
            unsigned r0 = ((w >> (2 * pp)) & 1u) ? (bfbits(p0) & 0xffff0000u) : 0u;
            unsigned r1 = ((w >> (2 * pp + 1)) & 1u) ? (bfbits(p1) & 0xffff0000u) : 0u;
            den += __builtin_bit_cast(float, r0) + __builtin_bit_cast(float, r1);
            dw[pp] = (r0 >> 16) | r1;                // low short = j even, high = j odd
        }
        int4 aw = make_int4((int)dw[0], (int)dw[1], (int)dw[2], (int)dw[3]);
        short8 afr = __builtin_bit_cast(short8, aw);
        acc0 = __builtin_amdgcn_mfma_f32_16x16x32_bf16(afr, __builtin_bit_cast(short8, blo), acc0, 0, 0, 0);
        acc1 = __builtin_amdgcn_mfma_f32_16x16x32_bf16(afr, __builtin_bit_cast(short8, bhi), acc1, 0, 0, 0);
    }

    // den: lane holds partial for row i=col over its 8-k slice; combine quads
    den += __shfl_xor(den, 16);
    den += __shfl_xor(den, 32);

    // C/D layout: col = lane&15, row = quad*4 + reg
    float* op = out + ((size_t)(b * NSZ) + i0) * (HH * ODIM) + h * ODIM + col;
#pragma unroll
    for (int r = 0; r < 4; r++) {
        int row = quad * 4 + r;
        float inv = 1.0f / __shfl(den, row);         // den for i = i0+row
        op[(size_t)row * (HH * ODIM)] = fmaxf(acc0[r] * inv, 0.f);
        op[(size_t)row * (HH * ODIM) + 16] = fmaxf(acc1[r] * inv, 0.f);
    }
}

extern "C" void kernel_launch(void* const* d_in, const int* in_sizes, int n_in,
                              void* d_out, int out_size, void* d_ws, size_t ws_size,
                              hipStream_t stream) {
    const float* x     = (const float*)d_in[0];
    const float* adj   = (const float*)d_in[1];
    const float* W     = (const float*)d_in[2];
    const float* a_src = (const float*)d_in[3];
    const float* a_dst = (const float*)d_in[4];
    float* out = (float*)d_out;

    float* ws = (float*)d_ws;
    float* asrc   = ws + WS_ASRC;
    float* adst   = ws + WS_ADST;
    unsigned* adjb = (unsigned*)(ws + WS_ADJB);
    int4* whf     = (int4*)(ws + WS_WHF);

    // adj bitmask: B*N*64 words, 8 lanes/word
    k_adjbits<<<dim3((BB * NSZ * 64 * 8) / 256), dim3(256), 0, stream>>>(adj, adjb);
    // projection + alphas + bf16 B-fragment pack
    k_wh<<<dim3(NSZ / 8, BB), dim3(256), 0, stream>>>(x, W, a_src, a_dst, whf, asrc, adst);
    // fused masked softmax + MFMA aggregation: 4096 waves, 4 per block
    k_gat<<<dim3(BB * HH * (NSZ / 16) / 4), dim3(256), 0, stream>>>(whf, asrc, adst, adjb, out);
}

// Round 3
// 179.473 us; speedup vs baseline: 2.2989x; 1.0172x over previous
//
#include <hip/hip_runtime.h>
#include <math.h>

#define BB 4
#define NSZ 2048
#define FDIM 128
#define ODIM 32
#define HH 8

typedef short short8 __attribute__((ext_vector_type(8)));
typedef float f32x4 __attribute__((ext_vector_type(4)));

// workspace layout (float units)
#define WS_EAP  0                 // float2[B*H*N] (EA, EA2)   = 131072 floats
#define WS_EBP  131072            // float2[B*H*N] (EB, EB2)   = 131072 floats
#define WS_ADJB 262144            // [B][N][64] u32            = 524288 words
#define WS_WHF  786432            // bf16 B-fragments          = 1048576 floats
// whf layout: int4[ ((b*H+h)*64 + jt)*2 + ot ][ 64 lanes ]  (16 B per lane-frag)

// round-to-nearest-even float -> bf16, result in TOP 16 bits
__device__ __forceinline__ unsigned bfbits(float f) {
    unsigned u = __builtin_bit_cast(unsigned, f);
    return u + 0x7fffu + ((u >> 16) & 1u);
}

// ---------------------------------------------------------------------------
// Fused prep kernel. Blocks [0,1024): Wh projection + whf fragment pack +
// alpha exps. Blocks [1024, 17408): adj bitmask pack. wh blocks first so the
// VALU/LDS-bound projection overlaps the HBM-bound adj sweep.
// ---------------------------------------------------------------------------
__global__ __launch_bounds__(256) void k_prep(const float* __restrict__ x,
                                              const float* __restrict__ adj,
                                              const float* __restrict__ W,
                                              const float* __restrict__ a_src,
                                              const float* __restrict__ a_dst,
                                              unsigned* __restrict__ adjb,
                                              int4* __restrict__ whf,
                                              float2* __restrict__ eap,
                                              float2* __restrict__ ebp) {
    __shared__ float xl[8 * FDIM];
    int t = threadIdx.x;

    if (blockIdx.x >= 1024) {
        // ---------------- adj bitmask part ----------------
        int g = (blockIdx.x - 1024) * 256 + t;      // [0, B*N*64*8)
        int l = g & 7;                              // lane within 8-group
        int word = g >> 3;                          // [0, B*N*64)
        int wk = word & 63;
        int row = word >> 6;                        // b*N + i
        int i = row & (NSZ - 1);
        const float4 v = *(const float4*)&adj[(size_t)row * NSZ + wk * 32 + l * 4];
        unsigned m = 0;
        if (v.x > 0.f) m |= 1u << (l * 4 + 0);
        if (v.y > 0.f) m |= 1u << (l * 4 + 1);
        if (v.z > 0.f) m |= 1u << (l * 4 + 2);
        if (v.w > 0.f) m |= 1u << (l * 4 + 3);
        m |= (unsigned)__shfl_xor((int)m, 1);
        m |= (unsigned)__shfl_xor((int)m, 2);
        m |= (unsigned)__shfl_xor((int)m, 4);
        if (l == 0) {
            int jb = i - wk * 32;
            if (jb >= 0 && jb < 32) m |= 1u << jb;  // self-loop
            adjb[word] = m;
        }
        return;
    }

    // ---------------- Wh projection part ----------------
    int bidx = blockIdx.x;
    int b = bidx >> 8;
    int n0 = (bidx & 255) * 8;
    // stage 8 x-rows (1024 floats) coalesced
    ((float4*)xl)[t] = ((const float4*)(x + (size_t)(b * NSZ + n0) * FDIM))[t];
    __syncthreads();

    int h = t >> 5, o = t & 31;
    float acc[8];
#pragma unroll
    for (int nn = 0; nn < 8; nn++) acc[nn] = 0.f;

    const float* wp = W + (size_t)h * FDIM * ODIM + o;
#pragma unroll 4
    for (int f = 0; f < FDIM; f += 4) {
        float w0 = wp[(f + 0) * ODIM];
        float w1 = wp[(f + 1) * ODIM];
        float w2 = wp[(f + 2) * ODIM];
        float w3 = wp[(f + 3) * ODIM];
#pragma unroll
        for (int nn = 0; nn < 8; nn++) {
            float4 xv = *(const float4*)&xl[nn * FDIM + f];
            acc[nn] += xv.x * w0 + xv.y * w1 + xv.z * w2 + xv.w * w3;
        }
    }

    float as = a_src[h * ODIM + o];
    float ad = a_dst[h * ODIM + o];
#pragma unroll
    for (int nn = 0; nn < 8; nn++) {
        float vs = acc[nn] * as;
        float vd = acc[nn] * ad;
#pragma unroll
        for (int mk = 16; mk; mk >>= 1) {
            vs += __shfl_xor(vs, mk);
            vd += __shfl_xor(vd, mk);
        }
        if (o == 0) {
            // separable exp factors: p = max(EA_i*EB_j, EA2_i*EB2_j) = exp(lrelu(s)-16)
            size_t idx = (size_t)(b * HH + h) * NSZ + n0 + nn;
            eap[idx] = make_float2(__expf(vs - 8.f), __expf(0.2f * vs - 8.f));
            ebp[idx] = make_float2(__expf(vd - 8.f), __expf(0.2f * vd - 8.f));
        }
    }

    // pack 8 bf16 (element j = acc[j]) and store one 16B fragment chunk
    int jt = n0 >> 5;
    int quad = (n0 >> 3) & 3;
    int ot = o >> 4;
    int lane = quad * 16 + (o & 15);
    unsigned d0 = (bfbits(acc[0]) >> 16) | (bfbits(acc[1]) & 0xffff0000u);
    unsigned d1 = (bfbits(acc[2]) >> 16) | (bfbits(acc[3]) & 0xffff0000u);
    unsigned d2 = (bfbits(acc[4]) >> 16) | (bfbits(acc[5]) & 0xffff0000u);
    unsigned d3 = (bfbits(acc[6]) >> 16) | (bfbits(acc[7]) & 0xffff0000u);
    whf[(((size_t)(b * HH + h) * 64 + jt) * 2 + ot) * 64 + lane] =
        make_int4((int)d0, (int)d1, (int)d2, (int)d3);
}

// ---------------------------------------------------------------------------
// Kernel 2: fused masked-softmax aggregation via MFMA. No LDS, no barriers,
// no exp in the loop: p = max(EA_i*EB_j, EA2_i*EB2_j), masked, packed to bf16
// via round-half-up + v_perm. den comes free from a 3rd MFMA vs all-ones B.
// ---------------------------------------------------------------------------
__global__ __launch_bounds__(256) void k_gat(const int4* __restrict__ whf,
                                             const float2* __restrict__ eap,
                                             const float2* __restrict__ ebp,
                                             const unsigned* __restrict__ adjb,
                                             float* __restrict__ out) {
    int lane = threadIdx.x & 63;
    int wid = blockIdx.x * 4 + (threadIdx.x >> 6);   // [0, 4096)
    int i0 = (wid & 127) << 4;
    int h = (wid >> 7) & 7;
    int b = wid >> 10;
    int col = lane & 15;
    int quad = lane >> 4;
    int qsh = quad * 8;

    float2 ea = eap[(size_t)(b * HH + h) * NSZ + i0 + col];  // (EA, EA2) for row i
    const float4* eb4 = (const float4*)(ebp + (size_t)(b * HH + h) * NSZ + qsh);
    const unsigned* abp = adjb + ((size_t)(b * NSZ) + i0 + col) * 64;
    const int4* bfp = whf + (size_t)(b * HH + h) * 8192 + lane;

    f32x4 acc0 = {0.f, 0.f, 0.f, 0.f};
    f32x4 acc1 = {0.f, 0.f, 0.f, 0.f};
    f32x4 accd = {0.f, 0.f, 0.f, 0.f};
    const int4 onesv = make_int4(0x3F803F80, 0x3F803F80, 0x3F803F80, 0x3F803F80);
    short8 bones = __builtin_bit_cast(short8, onesv);
    float eaa = ea.x, eab = ea.y;

#pragma unroll 2
    for (int jt = 0; jt < 64; jt++) {
        unsigned w = abp[jt] >> qsh;                 // 8 mask bits for this lane
        // 8 (EB, EB2) pairs for j = jt*32 + qsh + 0..7  (16 floats, 4 dwordx4)
        float4 l0 = eb4[jt * 16 + 0];
        float4 l1 = eb4[jt * 16 + 1];
        float4 l2 = eb4[jt * 16 + 2];
        float4 l3 = eb4[jt * 16 + 3];
        int4 blo = bfp[jt * 128];                    // B-frag, o 0..15
        int4 bhi = bfp[jt * 128 + 64];               // B-frag, o 16..31
        float p0, p1, p2, p3, p4, p5, p6, p7;
        p0 = fmaxf(eaa * l0.x, eab * l0.y);
        p1 = fmaxf(eaa * l0.z, eab * l0.w);
        p2 = fmaxf(eaa * l1.x, eab * l1.y);
        p3 = fmaxf(eaa * l1.z, eab * l1.w);
        p4 = fmaxf(eaa * l2.x, eab * l2.y);
        p5 = fmaxf(eaa * l2.z, eab * l2.w);
        p6 = fmaxf(eaa * l3.x, eab * l3.y);
        p7 = fmaxf(eaa * l3.z, eab * l3.w);
        p0 = (w & 1u)   ? p0 : 0.f;
        p1 = (w & 2u)   ? p1 : 0.f;
        p2 = (w & 4u)   ? p2 : 0.f;
        p3 = (w & 8u)   ? p3 : 0.f;
        p4 = (w & 16u)  ? p4 : 0.f;
        p5 = (w & 32u)  ? p5 : 0.f;
        p6 = (w & 64u)  ? p6 : 0.f;
        p7 = (w & 128u) ? p7 : 0.f;
        // round-half-up + byte-perm pack: dword = (odd_hi16 << 16) | even_hi16
        unsigned u0 = __builtin_bit_cast(unsigned, p0) + 0x8000u;
        unsigned u1 = __builtin_bit_cast(unsigned, p1) + 0x8000u;
        unsigned u2 = __builtin_bit_cast(unsigned, p2) + 0x8000u;
        unsigned u3 = __builtin_bit_cast(unsigned, p3) + 0x8000u;
        unsigned u4 = __builtin_bit_cast(unsigned, p4) + 0x8000u;
        unsigned u5 = __builtin_bit_cast(unsigned, p5) + 0x8000u;
        unsigned u6 = __builtin_bit_cast(unsigned, p6) + 0x8000u;
        unsigned u7 = __builtin_bit_cast(unsigned, p7) + 0x8000u;
        int4 aw = make_int4((int)__builtin_amdgcn_perm(u1, u0, 0x07060302),
                            (int)__builtin_amdgcn_perm(u3, u2, 0x07060302),
                            (int)__builtin_amdgcn_perm(u5, u4, 0x07060302),
                            (int)__builtin_amdgcn_perm(u7, u6, 0x07060302));
        short8 afr = __builtin_bit_cast(short8, aw);
        acc0 = __builtin_amdgcn_mfma_f32_16x16x32_bf16(afr, __builtin_bit_cast(short8, blo), acc0, 0, 0, 0);
        acc1 = __builtin_amdgcn_mfma_f32_16x16x32_bf16(afr, __builtin_bit_cast(short8, bhi), acc1, 0, 0, 0);
        accd = __builtin_amdgcn_mfma_f32_16x16x32_bf16(afr, bones, accd, 0, 0, 0);
    }

    // C/D layout: col = lane&15, row = quad*4 + reg; accd[r] = row-sum = den
    float* op = out + ((size_t)(b * NSZ) + i0) * (HH * ODIM) + h * ODIM + col;
#pragma unroll
    for (int r = 0; r < 4; r++) {
        int row = quad * 4 + r;
        float inv = 1.0f / accd[r];
        op[(size_t)row * (HH * ODIM)] = fmaxf(acc0[r] * inv, 0.f);
        op[(size_t)row * (HH * ODIM) + 16] = fmaxf(acc1[r] * inv, 0.f);
    }
}

extern "C" void kernel_launch(void* const* d_in, const int* in_sizes, int n_in,
                              void* d_out, int out_size, void* d_ws, size_t ws_size,
                              hipStream_t stream) {
    const float* x     = (const float*)d_in[0];
    const float* adj   = (const float*)d_in[1];
    const float* W     = (const float*)d_in[2];
    const float* a_src = (const float*)d_in[3];
    const float* a_dst = (const float*)d_in[4];
    float* out = (float*)d_out;

    float* ws = (float*)d_ws;
    float2* eap    = (float2*)(ws + WS_EAP);
    float2* ebp    = (float2*)(ws + WS_EBP);
    unsigned* adjb = (unsigned*)(ws + WS_ADJB);
    int4* whf      = (int4*)(ws + WS_WHF);

    // fused prep: 1024 wh blocks + 16384 adj-bitmask blocks, one launch
    k_prep<<<dim3(1024 + 16384), dim3(256), 0, stream>>>(x, adj, W, a_src, a_dst,
                                                         adjb, whf, eap, ebp);
    // fused masked softmax + MFMA aggregation: 4096 waves, 4 per block
    k_gat<<<dim3(BB * HH * (NSZ / 16) / 4), dim3(256), 0, stream>>>(whf, eap, ebp, adjb, out);
}